// Round 1
// baseline (265.736 us; speedup 1.0000x reference)
//
#include <hip/hip_runtime.h>
#include <stdint.h>

// CIN (xDeepFM) forward, MI355X bf16-MFMA implementation.
// Layers: out[b,d,o] = relu(bias[o] + sum_{f,h'} x0[b,f,d]*h[b,h',d]*W[f*Hp+h',o])
//   layer0: Hp=39 (padded to 64), layers1/2: Hp=128. B=1024, F=39, D=32, N=256.
// Workspace layout (needs ~16.9 MB):
//   WT0 bf16 [256][2496], WT1 bf16 [256][4992], WT2 bf16 [256][4992]  (W^T, k-padded)
//   h_buf bf16 [1024][32][128]  (layer output halves, d-major)
//   fsum f32 [1024][512]        (per-channel d-sums; every slot written each call)

typedef __attribute__((ext_vector_type(8))) short short8;
typedef __attribute__((ext_vector_type(8))) unsigned short us8;
typedef __attribute__((ext_vector_type(4))) float f32x4;

__device__ __forceinline__ unsigned short f32_to_bf16(float f) {
  uint32_t u = __float_as_uint(f);
  return (unsigned short)((u + 0x7FFFu + ((u >> 16) & 1u)) >> 16);  // RNE
}
__device__ __forceinline__ float bf16_to_f32(unsigned short s) {
  return __uint_as_float(((uint32_t)s) << 16);
}
__device__ __forceinline__ uint32_t cvt_pk_bf16(float lo, float hi) {
  uint32_t r;
  asm("v_cvt_pk_bf16_f32 %0, %1, %2" : "=v"(r) : "v"(lo), "v"(hi));
  return r;
}

// ---------------- prep: W (K,256) f32  ->  WT (256, KPAD) bf16, transposed ----
// blocks [0,312): WT0 (KPAD=2496, k=f*64+hh, zero for hh>=39)
// blocks [312,936): WT1 ; [936,1560): WT2  (KPAD=4992, identity k)
__global__ void prep_wt(const float* __restrict__ W0, const float* __restrict__ W1,
                        const float* __restrict__ W2, unsigned short* __restrict__ WT0,
                        unsigned short* __restrict__ WT1, unsigned short* __restrict__ WT2) {
  int blk = blockIdx.x;
  const float* W;
  unsigned short* WT;
  int KPAD, kp0;
  bool l0 = false;
  if (blk < 312) { W = W0; WT = WT0; KPAD = 2496; kp0 = blk * 8; l0 = true; }
  else if (blk < 936) { W = W1; WT = WT1; KPAD = 4992; kp0 = (blk - 312) * 8; }
  else { W = W2; WT = WT2; KPAD = 4992; kp0 = (blk - 936) * 8; }

  __shared__ unsigned short lds[8][257];
  int t = threadIdx.x;  // 256 = n
  #pragma unroll
  for (int kk = 0; kk < 8; ++kk) {
    int kp = kp0 + kk;
    float v;
    if (l0) {
      int f = kp >> 6, hh = kp & 63;
      v = (hh < 39) ? W[(f * 39 + hh) * 256 + t] : 0.f;
    } else {
      v = W[kp * 256 + t];
    }
    lds[kk][t] = f32_to_bf16(v);
  }
  __syncthreads();
  us8 o;
  #pragma unroll
  for (int kk = 0; kk < 8; ++kk) o[kk] = lds[kk][t];
  *(us8*)(&WT[(size_t)t * KPAD + kp0]) = o;
}

// ---------------- main layer kernel ------------------------------------------
// grid 256 blocks x 512 threads. Block: 4 batch samples (M=128 rows), 8 waves
// as 2 M-groups x 4 N-groups, wave tile 64x64 via 16x16x32 bf16 MFMA.
template <int LAYER>
__global__ __launch_bounds__(512) void cin_layer(
    const float* __restrict__ x, const unsigned short* __restrict__ hin,
    const unsigned short* __restrict__ WT, const float* __restrict__ bias,
    unsigned short* __restrict__ hout, float* __restrict__ fsum) {
  constexpr int HPAD = (LAYER == 0) ? 64 : 128;
  constexpr int HROW = HPAD + 8;     // LDS row pad (bank-friendly)
  constexpr int KPAD = 39 * HPAD;
  constexpr int HC = HPAD / 32;
  constexpr int NIT = HC * 39;

  __shared__ __align__(16) unsigned short hT[4][32][HROW];    // h transposed [b'][d][h']
  __shared__ __align__(16) unsigned short x0T[4][32][40];     // x0 transposed [b'][d][f]
  __shared__ __align__(16) unsigned short wtile[2][256][40];  // W tile [n][kk], dbuf

  const int tid = threadIdx.x;
  const int bbase = blockIdx.x * 4;

  // ---- stage x0T (and hT for layer 0) from x (b,39,32) f32
  for (int idx = tid; idx < 4 * 1248; idx += 512) {
    int b = idx / 1248;
    int rem = idx - b * 1248;
    int f = rem >> 5, d = rem & 31;
    unsigned short us = f32_to_bf16(x[(bbase + b) * 1248 + rem]);
    x0T[b][d][f] = us;
    if (LAYER == 0) hT[b][d][f] = us;
  }
  if (LAYER == 0) {
    for (int idx = tid; idx < 4 * 32 * 25; idx += 512) {  // zero h' in [39,64)
      int b = idx / 800;
      int rem = idx - b * 800;
      int d = rem / 25, p = rem - d * 25;
      hT[b][d][39 + p] = 0;
    }
  } else {
    for (int idx = tid; idx < 4 * 32 * 16; idx += 512) {  // copy h_buf bf16 [b][d][128]
      int b = idx >> 9, rem = idx & 511;
      int d = rem >> 4, c = rem & 15;
      us8 v = *(const us8*)(&hin[(((bbase + b) * 32 + d) << 7) + c * 8]);
      *(us8*)(&hT[b][d][c * 8]) = v;
    }
  }

  const int lane = tid & 63;
  const int w = tid >> 6;
  const int wy = w >> 2;  // M-group 0..1
  const int wx = w & 3;   // N-group 0..3
  const int l15 = lane & 15;
  const int g = lane >> 4;

  f32x4 acc[4][4];
  #pragma unroll
  for (int i = 0; i < 4; ++i)
    #pragma unroll
    for (int j = 0; j < 4; ++j) acc[i][j] = (f32x4){0.f, 0.f, 0.f, 0.f};

  int rbb[4], rdd[4];  // per m-tile: which b' and d this lane's A-row maps to
  #pragma unroll
  for (int mt = 0; mt < 4; ++mt) {
    int row = wy * 64 + mt * 16 + l15;
    rbb[mt] = row >> 5;
    rdd[mt] = row & 31;
  }

  // W staging addresses: thread -> (n = tid>>2 [+128], 16B chunk c = tid&3)
  const int sn = tid >> 2, sc = tid & 3;
  const unsigned short* wsrc0 = WT + (size_t)sn * KPAD + sc * 8;
  const unsigned short* wsrc1 = WT + (size_t)(sn + 128) * KPAD + sc * 8;

  us8 s0 = *(const us8*)(wsrc0);  // it=0 tile (kb=0)
  us8 s1 = *(const us8*)(wsrc1);
  *(us8*)(&wtile[0][sn][sc * 8]) = s0;
  *(us8*)(&wtile[0][sn + 128][sc * 8]) = s1;
  __syncthreads();  // covers hT/x0T and wtile[0]

  float hf[4][8];  // unpacked h fragment (per m-tile), reused across the f loop
  int it = 0;
  for (int hc = 0; hc < HC; ++hc) {
    #pragma unroll
    for (int mt = 0; mt < 4; ++mt) {
      us8 h8 = *(const us8*)(&hT[rbb[mt]][rdd[mt]][hc * 32 + g * 8]);
      #pragma unroll
      for (int e = 0; e < 8; ++e) hf[mt][e] = bf16_to_f32(h8[e]);
    }
    for (int f = 0; f < 39; ++f, ++it) {
      const int buf = it & 1;
      const bool more = (it + 1 < NIT);
      if (more) {  // prefetch next W tile into regs (latency hides under compute)
        int nf = (f + 1 < 39) ? f + 1 : 0;
        int nhc = (f + 1 < 39) ? hc : hc + 1;
        int kb = nf * HPAD + nhc * 32;
        s0 = *(const us8*)(wsrc0 + kb);
        s1 = *(const us8*)(wsrc1 + kb);
      }
      // A fragments: a[k] = bf16(x0[b,f,d] * h[b,k,d])
      short8 afr[4];
      #pragma unroll
      for (int mt = 0; mt < 4; ++mt) {
        float xs = bf16_to_f32(x0T[rbb[mt]][rdd[mt]][f]);
        union { uint32_t u[4]; short8 v; } au;
        #pragma unroll
        for (int i = 0; i < 4; ++i)
          au.u[i] = cvt_pk_bf16(hf[mt][2 * i] * xs, hf[mt][2 * i + 1] * xs);
        afr[mt] = au.v;
      }
      // B fragments from LDS W tile (same per-lane k-map as A => layout-safe)
      short8 bfr[4];
      #pragma unroll
      for (int nt = 0; nt < 4; ++nt) {
        int n = wx * 64 + nt * 16 + l15;
        union { us8 u; short8 v; } bu;
        bu.u = *(const us8*)(&wtile[buf][n][g * 8]);
        bfr[nt] = bu.v;
      }
      #pragma unroll
      for (int mt = 0; mt < 4; ++mt)
        #pragma unroll
        for (int nt = 0; nt < 4; ++nt)
          acc[mt][nt] =
              __builtin_amdgcn_mfma_f32_16x16x32_bf16(afr[mt], bfr[nt], acc[mt][nt], 0, 0, 0);
      __syncthreads();
      if (more) {
        *(us8*)(&wtile[buf ^ 1][sn][sc * 8]) = s0;
        *(us8*)(&wtile[buf ^ 1][sn + 128][sc * 8]) = s1;
      }
      __syncthreads();
    }
  }

  // ---- epilogue: relu(acc+bias); o<128 -> h for next layer; else d-sums -> fsum
  float bv[4];
  #pragma unroll
  for (int nt = 0; nt < 4; ++nt) bv[nt] = bias[wx * 64 + nt * 16 + l15];

  if (LAYER < 2 && wx < 2) {  // h half (o in [0,128))
    #pragma unroll
    for (int mt = 0; mt < 4; ++mt) {
      #pragma unroll
      for (int nt = 0; nt < 4; ++nt) {
        int o = wx * 64 + nt * 16 + l15;
        #pragma unroll
        for (int r = 0; r < 4; ++r) {
          int row = wy * 64 + mt * 16 + g * 4 + r;  // C/D: row=(lane>>4)*4+reg, col=lane&15
          int bb = row >> 5, dd = row & 31;
          float v = fmaxf(acc[mt][nt][r] + bv[nt], 0.f);
          hout[(((bbase + bb) * 32 + dd) << 7) + o] = f32_to_bf16(v);
        }
      }
    }
  } else {  // finals: sum over d, store to fsum[b][j]
    #pragma unroll
    for (int nt = 0; nt < 4; ++nt) {
      float sub[2] = {0.f, 0.f};  // per b-half within this wave's 64 rows
      #pragma unroll
      for (int mt = 0; mt < 4; ++mt) {
        #pragma unroll
        for (int r = 0; r < 4; ++r) {
          float v = fmaxf(acc[mt][nt][r] + bv[nt], 0.f);
          sub[mt >> 1] += v;
        }
      }
      #pragma unroll
      for (int h = 0; h < 2; ++h) {
        sub[h] += __shfl_xor(sub[h], 16);
        sub[h] += __shfl_xor(sub[h], 32);
      }
      if (lane < 16) {
        int o = wx * 64 + nt * 16 + l15;
        int j = (LAYER == 0) ? (o - 128) : ((LAYER == 1) ? o : (256 + o));
        int b0 = bbase + wy * 2;
        fsum[b0 * 512 + j] = sub[0];
        fsum[(b0 + 1) * 512 + j] = sub[1];
      }
    }
  }
}

// ---------------- finalize: out[b] = fc_b + sum_j fsum[b][j]*fc_w[j] ----------
__global__ void finalize(const float* __restrict__ fsum, const float* __restrict__ fc_w,
                         const float* __restrict__ fc_b, float* __restrict__ out) {
  int b = blockIdx.x;
  int lane = threadIdx.x;  // 64
  const float* fs = fsum + (size_t)b * 512;
  float s = 0.f;
  #pragma unroll
  for (int k = 0; k < 8; ++k) {
    int j = k * 64 + lane;
    s += fs[j] * fc_w[j];
  }
  #pragma unroll
  for (int off = 32; off; off >>= 1) s += __shfl_xor(s, off);
  if (lane == 0) out[b] = s + fc_b[0];
}

extern "C" void kernel_launch(void* const* d_in, const int* in_sizes, int n_in,
                              void* d_out, int out_size, void* d_ws, size_t ws_size,
                              hipStream_t stream) {
  const float* x = (const float*)d_in[0];
  const float* W0 = (const float*)d_in[1];
  const float* b0 = (const float*)d_in[2];
  const float* W1 = (const float*)d_in[3];
  const float* b1 = (const float*)d_in[4];
  const float* W2 = (const float*)d_in[5];
  const float* b2 = (const float*)d_in[6];
  const float* fc_w = (const float*)d_in[7];
  const float* fc_b = (const float*)d_in[8];
  float* out = (float*)d_out;

  char* ws = (char*)d_ws;
  size_t oWT0 = 0;
  size_t oWT1 = oWT0 + (size_t)256 * 2496 * 2;  // 1,277,952
  size_t oWT2 = oWT1 + (size_t)256 * 4992 * 2;  // +2,555,904
  size_t oH = oWT2 + (size_t)256 * 4992 * 2;
  size_t oFS = oH + (size_t)1024 * 32 * 128 * 2;  // +8,388,608
  // total = oFS + 1024*512*4 = ~16.9 MB (assumed <= ws_size)
  unsigned short* WT0 = (unsigned short*)(ws + oWT0);
  unsigned short* WT1 = (unsigned short*)(ws + oWT1);
  unsigned short* WT2 = (unsigned short*)(ws + oWT2);
  unsigned short* hbuf = (unsigned short*)(ws + oH);
  float* fsum = (float*)(ws + oFS);

  prep_wt<<<1560, 256, 0, stream>>>(W0, W1, W2, WT0, WT1, WT2);
  cin_layer<0><<<256, 512, 0, stream>>>(x, nullptr, WT0, b0, hbuf, fsum);
  cin_layer<1><<<256, 512, 0, stream>>>(x, hbuf, WT1, b1, hbuf, fsum);
  cin_layer<2><<<256, 512, 0, stream>>>(x, hbuf, WT2, b2, nullptr, fsum);
  finalize<<<1024, 64, 0, stream>>>(fsum, fc_w, fc_b, out);
}